// Round 2
// baseline (21791.856 us; speedup 1.0000x reference)
//
#include <hip/hip_runtime.h>
#include <stdint.h>
#include <stddef.h>

typedef __attribute__((ext_vector_type(8))) short short8;
typedef __attribute__((ext_vector_type(8))) _Float16 half8;
typedef __attribute__((ext_vector_type(4))) float f32x4;

#define T_  256
#define B_  256
#define C_  32
#define H_  512
#define O_  32
#define KB1 17   // ceil(544/32)
#define NT1 64   // 64 col-tiles of 16 over [W1|Wg] (1024 cols)
#define KB2 16
#define NT2 32

__device__ __forceinline__ short f2h(float f) {
  _Float16 h = (_Float16)f;
  return __builtin_bit_cast(short, h);
}
__device__ __forceinline__ void f2hl(float f, short& hi, short& lo) {
  _Float16 h = (_Float16)f;
  _Float16 l = (_Float16)(f - (float)h);
  hi = __builtin_bit_cast(short, h);
  lo = __builtin_bit_cast(short, l);
}
__device__ __forceinline__ float fast_tanh(float x) {
  float e = __expf(2.0f * x);
  return 1.0f - 2.0f / (e + 1.0f);
}
__device__ __forceinline__ float fast_sigmoid(float x) {
  return 1.0f / (1.0f + __expf(-x));
}
__device__ __forceinline__ f32x4 mfma16(half8 a, half8 b, f32x4 c) {
  return __builtin_amdgcn_mfma_f32_16x16x32_f16(a, b, c, 0, 0, 0);
}
__device__ __forceinline__ half8 ld8(const short* p) {
  return *(const half8*)p;
}

// ---------------- weight packing ----------------
// Packed tile layout: elem ((kb*NT + nt)*64 + lane)*8 + j holds
// W[kb*32 + (lane>>4)*8 + j][nt*16 + (lane&15)], zero-filled OOB.

__global__ void pack_b1s(const float* __restrict__ W1, const float* __restrict__ Wg,
                         short* __restrict__ hi, short* __restrict__ lo) {
  int gid = blockIdx.x * 256 + threadIdx.x;          // 17*64*512 = 557056
  if (gid >= KB1 * NT1 * 512) return;
  int j = gid & 7, lane = (gid >> 3) & 63, tile = gid >> 9;
  int nt = tile % NT1, kb = tile / NT1;
  int k = kb * 32 + ((lane >> 4) << 3) + j;          // 0..543
  int n = ((nt & 31) << 4) + (lane & 15);
  float v = 0.f;
  if (nt < 32)      v = W1[k * H_ + n];
  else if (k < H_)  v = Wg[k * H_ + n];
  short h, l;
  f2hl(v, h, l);
  hi[gid] = h; lo[gid] = l;
}

__global__ void pack_s(const float* __restrict__ src, short* __restrict__ hi,
                       short* __restrict__ lo, int Ksrc, int Nsrc, int KB, int NT) {
  int gid = blockIdx.x * 256 + threadIdx.x;
  if (gid >= KB * NT * 512) return;
  int j = gid & 7, lane = (gid >> 3) & 63, tile = gid >> 9;
  int nt = tile % NT, kb = tile / NT;
  int k = kb * 32 + ((lane >> 4) << 3) + j;
  int n = (nt << 4) + (lane & 15);
  float v = (k < Ksrc && n < Nsrc) ? src[k * Nsrc + n] : 0.f;
  short h, l;
  f2hl(v, h, l);
  hi[gid] = h;
  if (lo) lo[gid] = l;
}

// ---------------- SDE scan kernel ----------------
// 16 WGs x 1024 threads (16 waves). WG owns 16 batch rows.
// A_ext row layout in LDS: [y_hi(0..511) | x_hi(512..543) | y_lo(544..1055) | x_lo(1056..1087)]
// preact = A_hi@W_hi + A_lo@W_hi + A_hi@W_lo   (W_hi frag shared by terms 1+2)
__global__ __launch_bounds__(1024) void sde_kernel(
    const float* __restrict__ times, const float* __restrict__ coeffs,
    const float* __restrict__ dW,
    const float* __restrict__ b_init, const float* __restrict__ b1,
    const float* __restrict__ b2, const float* __restrict__ bg,
    const short* __restrict__ B1h, const short* __restrict__ B1l,
    const short* __restrict__ W2h, const short* __restrict__ W2l,
    const short* __restrict__ WIh, const short* __restrict__ WIl,
    short* __restrict__ zt) {
  __shared__ short y_lds[16][1096];
  __shared__ short h_lds[16][1032];   // [h_hi(0..511) | h_lo(512..1023)]
  __shared__ float red[16];

  const int tid = threadIdx.x;
  const int w = tid >> 6, l = tid & 63;
  const int ra = l & 15;
  const int kq = l >> 4;
  const int B0 = blockIdx.x << 4;

  float d = 1e30f;
  if (tid < T_ - 1) d = times[tid + 1] - times[tid];
  #pragma unroll
  for (int s = 32; s >= 1; s >>= 1) d = fminf(d, __shfl_xor(d, s, 64));
  if (l == 0) red[w] = d;

  if (tid < 512) {
    int r = tid >> 5, c = tid & 31;
    short h, lo;
    f2hl(coeffs[(size_t)(B0 + r) * (T_ * C_) + c], h, lo);
    y_lds[r][512 + c] = h;
    y_lds[r][1056 + c] = lo;
  }
  __syncthreads();
  float m = red[0];
  #pragma unroll
  for (int i = 1; i < 16; ++i) m = fminf(m, red[i]);
  const float dt = fmaxf(m, 0.001f);
  const float sq = sqrtf(dt);

  const int c0 = (w << 5) + ra;
  const int c1 = c0 + 16;
  const float b1_0 = b1[c0], b1_1 = b1[c1];
  const float b2_0 = b2[c0], b2_1 = b2[c1];
  const float bg_0 = bg[c0], bg_1 = bg[c1];
  const float bi_0 = b_init[c0], bi_1 = b_init[c1];
  const int nt0 = w << 1, nt1 = nt0 + 1;

  // register-cache W2_hi fragments for this wave's two tiles (held 255 steps)
  half8 w2h0[16], w2h1[16];
  #pragma unroll
  for (int kb = 0; kb < 16; ++kb) {
    const short* bp = W2h + kb * (NT2 * 512) + (l << 3);
    w2h0[kb] = ld8(bp + (nt0 << 9));
    w2h1[kb] = ld8(bp + (nt1 << 9));
  }

  // ---- z0 = x0 @ W_init + b_init (split) ----
  float yreg0[4], yreg1[4];
  {
    half8 ah = ld8(&y_lds[ra][512 + (kq << 3)]);
    half8 al = ld8(&y_lds[ra][1056 + (kq << 3)]);
    half8 bh0 = ld8(WIh + (((nt0) << 6) + l) * 8);
    half8 bh1 = ld8(WIh + (((nt1) << 6) + l) * 8);
    half8 bl0 = ld8(WIl + (((nt0) << 6) + l) * 8);
    half8 bl1 = ld8(WIl + (((nt1) << 6) + l) * 8);
    f32x4 Z = {0.f, 0.f, 0.f, 0.f};
    f32x4 A0 = mfma16(ah, bh0, Z); A0 = mfma16(al, bh0, A0); A0 = mfma16(ah, bl0, A0);
    f32x4 A1 = mfma16(ah, bh1, Z); A1 = mfma16(al, bh1, A1); A1 = mfma16(ah, bl1, A1);
    #pragma unroll
    for (int r = 0; r < 4; ++r) { yreg0[r] = A0[r] + bi_0; yreg1[r] = A1[r] + bi_1; }
  }
  #pragma unroll
  for (int r = 0; r < 4; ++r) {
    short h, lo;
    f2hl(yreg0[r], h, lo);
    y_lds[(kq << 2) + r][c0] = h; y_lds[(kq << 2) + r][544 + c0] = lo;
    f2hl(yreg1[r], h, lo);
    y_lds[(kq << 2) + r][c1] = h; y_lds[(kq << 2) + r][544 + c1] = lo;
  }
  __syncthreads();

  // ---- main scan ----
  for (int k = 0; k < T_ - 1; ++k) {
    float dw0[4], dw1[4];
    {
      const float* dwb = dW + ((size_t)k * B_ + B0) * H_;
      #pragma unroll
      for (int r = 0; r < 4; ++r) {
        dw0[r] = __builtin_nontemporal_load(dwb + ((kq << 2) + r) * H_ + c0);
        dw1[r] = __builtin_nontemporal_load(dwb + ((kq << 2) + r) * H_ + c1);
      }
    }
    // phase A: preact over K_ext
    f32x4 A0 = {0,0,0,0}, A1 = {0,0,0,0}, A2 = {0,0,0,0}, A3 = {0,0,0,0};
    for (int kb = 0; kb < KB1; ++kb) {
      half8 ah = ld8(&y_lds[ra][(kb << 5) + (kq << 3)]);
      half8 al = ld8(&y_lds[ra][544 + (kb << 5) + (kq << 3)]);
      const short* bph = B1h + (size_t)kb * (NT1 * 512) + (l << 3);
      const short* bpl = B1l + (size_t)kb * (NT1 * 512) + (l << 3);
      half8 h0 = ld8(bph + (nt0 << 9));
      half8 h1 = ld8(bph + (nt1 << 9));
      half8 h2 = ld8(bph + ((32 + nt0) << 9));
      half8 h3 = ld8(bph + ((32 + nt1) << 9));
      half8 l0 = ld8(bpl + (nt0 << 9));
      half8 l1 = ld8(bpl + (nt1 << 9));
      half8 l2 = ld8(bpl + ((32 + nt0) << 9));
      half8 l3 = ld8(bpl + ((32 + nt1) << 9));
      A0 = mfma16(ah, h0, A0); A0 = mfma16(al, h0, A0); A0 = mfma16(ah, l0, A0);
      A1 = mfma16(ah, h1, A1); A1 = mfma16(al, h1, A1); A1 = mfma16(ah, l1, A1);
      A2 = mfma16(ah, h2, A2); A2 = mfma16(al, h2, A2); A2 = mfma16(ah, l2, A2);
      A3 = mfma16(ah, h3, A3); A3 = mfma16(al, h3, A3); A3 = mfma16(ah, l3, A3);
    }
    float g0[4], g1[4];
    #pragma unroll
    for (int r = 0; r < 4; ++r) {
      short h, lo;
      f2hl(fast_tanh(A0[r] + b1_0), h, lo);
      h_lds[(kq << 2) + r][c0] = h; h_lds[(kq << 2) + r][512 + c0] = lo;
      f2hl(fast_tanh(A1[r] + b1_1), h, lo);
      h_lds[(kq << 2) + r][c1] = h; h_lds[(kq << 2) + r][512 + c1] = lo;
      g0[r] = fast_sigmoid(A2[r] + bg_0);
      g1[r] = fast_sigmoid(A3[r] + bg_1);
    }
    __syncthreads();
    // phase B: f = tanh(h @ W2 + b2)   (W2_hi from registers, W2_lo streamed)
    f32x4 F0 = {0,0,0,0}, F1 = {0,0,0,0};
    #pragma unroll
    for (int kb = 0; kb < KB2; ++kb) {
      half8 ah = ld8(&h_lds[ra][(kb << 5) + (kq << 3)]);
      half8 al = ld8(&h_lds[ra][512 + (kb << 5) + (kq << 3)]);
      const short* bpl = W2l + (size_t)kb * (NT2 * 512) + (l << 3);
      half8 l0 = ld8(bpl + (nt0 << 9));
      half8 l1 = ld8(bpl + (nt1 << 9));
      F0 = mfma16(ah, w2h0[kb], F0); F0 = mfma16(al, w2h0[kb], F0); F0 = mfma16(ah, l0, F0);
      F1 = mfma16(ah, w2h1[kb], F1); F1 = mfma16(al, w2h1[kb], F1); F1 = mfma16(ah, l1, F1);
    }
    #pragma unroll
    for (int r = 0; r < 4; ++r) {
      float f0 = fast_tanh(F0[r] + b2_0);
      float f1 = fast_tanh(F1[r] + b2_1);
      yreg0[r] += f0 * dt + g0[r] * (sq * dw0[r]);
      yreg1[r] += f1 * dt + g1[r] * (sq * dw1[r]);
    }
    if (k >= T_ - 1 - O_) {
      const int t = k - (T_ - 1 - O_);
      #pragma unroll
      for (int r = 0; r < 4; ++r) {
        size_t base = ((size_t)(B0 + (kq << 2) + r) * O_ + t) * H_;
        __builtin_nontemporal_store(f2h(yreg0[r]), zt + base + c0);
        __builtin_nontemporal_store(f2h(yreg1[r]), zt + base + c1);
      }
    }
    #pragma unroll
    for (int r = 0; r < 4; ++r) {
      short h, lo;
      f2hl(yreg0[r], h, lo);
      y_lds[(kq << 2) + r][c0] = h; y_lds[(kq << 2) + r][544 + c0] = lo;
      f2hl(yreg1[r], h, lo);
      y_lds[(kq << 2) + r][c1] = h; y_lds[(kq << 2) + r][544 + c1] = lo;
    }
    if (k < T_ - 2 && tid < 512) {
      int r = tid >> 5, c = tid & 31;
      short h, lo;
      f2hl(coeffs[(size_t)(B0 + r) * (T_ * C_) + (size_t)(k + 1) * C_ + c], h, lo);
      y_lds[r][512 + c] = h;
      y_lds[r][1056 + c] = lo;
    }
    __syncthreads();
  }
}

// ---------------- head kernel (single fp16 — one-shot, no compounding) ----
__global__ __launch_bounds__(256) void head_kernel(
    const short* __restrict__ zt, const short* __restrict__ Wh1p,
    const short* __restrict__ Wh2p, const float* __restrict__ bh1,
    const float* __restrict__ bh2, float* __restrict__ out) {
  __shared__ short a_lds[32][520];
  __shared__ short h2_lds[32][520];
  const int tid = threadIdx.x;
  const int w = tid >> 6, l = tid & 63;
  const int ra = l & 15, kq = l >> 4;
  const int r0 = blockIdx.x << 5;

  const short* zb = zt + (size_t)r0 * H_;
  #pragma unroll
  for (int i = 0; i < 8; ++i) {
    int cidx = i * 256 + tid;            // 2048 short8 chunks
    int row = cidx >> 6, cc = (cidx & 63) << 3;
    *(short8*)&a_lds[row][cc] = *(const short8*)(zb + row * H_ + cc);
  }
  __syncthreads();

  f32x4 acc[2][8];
  #pragma unroll
  for (int mt = 0; mt < 2; ++mt)
    #pragma unroll
    for (int i = 0; i < 8; ++i) acc[mt][i] = (f32x4){0.f, 0.f, 0.f, 0.f};
  for (int kb = 0; kb < 16; ++kb) {
    half8 a0 = ld8(&a_lds[ra][(kb << 5) + (kq << 3)]);
    half8 a1 = ld8(&a_lds[16 + ra][(kb << 5) + (kq << 3)]);
    const short* bp = Wh1p + (size_t)kb * (32 * 512) + (l << 3);
    #pragma unroll
    for (int i = 0; i < 8; ++i) {
      half8 b = ld8(bp + ((8 * w + i) << 9));
      acc[0][i] = mfma16(a0, b, acc[0][i]);
      acc[1][i] = mfma16(a1, b, acc[1][i]);
    }
  }
  #pragma unroll
  for (int i = 0; i < 8; ++i) {
    int col = ((8 * w + i) << 4) + ra;
    float bb = bh1[col];
    #pragma unroll
    for (int mt = 0; mt < 2; ++mt)
      #pragma unroll
      for (int r = 0; r < 4; ++r) {
        float h = acc[mt][i][r] + bb;
        h = h > 0.f ? h : 0.f;
        h2_lds[(mt << 4) + (kq << 2) + r][col] = f2h(h);
      }
  }
  __syncthreads();

  {
    int mt = w >> 1, nt = w & 1;
    f32x4 F = {0.f, 0.f, 0.f, 0.f};
    for (int kb = 0; kb < 16; ++kb) {
      half8 a = ld8(&h2_lds[(mt << 4) + ra][(kb << 5) + (kq << 3)]);
      half8 b = ld8(Wh2p + (size_t)((kb * 2 + nt) * 64 + l) * 8);
      F = mfma16(a, b, F);
    }
    int col = (nt << 4) + ra;
    float bb = bh2[col];
    #pragma unroll
    for (int r = 0; r < 4; ++r)
      out[(size_t)(r0 + (mt << 4) + (kq << 2) + r) * O_ + col] = F[r] + bb;
  }
}

// ---------------- launcher ----------------
extern "C" void kernel_launch(void* const* d_in, const int* in_sizes, int n_in,
                              void* d_out, int out_size, void* d_ws, size_t ws_size,
                              hipStream_t stream) {
  (void)in_sizes; (void)n_in; (void)out_size; (void)ws_size;
  const float* times  = (const float*)d_in[0];
  const float* coeffs = (const float*)d_in[1];
  const float* dW     = (const float*)d_in[3];
  const float* W_init = (const float*)d_in[4];
  const float* b_init = (const float*)d_in[5];
  const float* W1     = (const float*)d_in[6];
  const float* b1     = (const float*)d_in[7];
  const float* W2     = (const float*)d_in[8];
  const float* b2     = (const float*)d_in[9];
  const float* Wg     = (const float*)d_in[10];
  const float* bg     = (const float*)d_in[11];
  const float* Wh1    = (const float*)d_in[12];
  const float* bh1    = (const float*)d_in[13];
  const float* Wh2    = (const float*)d_in[14];
  const float* bh2    = (const float*)d_in[15];
  float* out = (float*)d_out;
  char* ws = (char*)d_ws;

  short* B1h  = (short*)(ws + 0);         // 1,114,112
  short* B1l  = (short*)(ws + 1114112);   // 1,114,112
  short* W2h  = (short*)(ws + 2228224);   //   524,288
  short* W2l  = (short*)(ws + 2752512);   //   524,288
  short* WIh  = (short*)(ws + 3276800);   //    32,768
  short* WIl  = (short*)(ws + 3309568);   //    32,768
  short* Wh1p = (short*)(ws + 3342336);   //   524,288
  short* Wh2p = (short*)(ws + 3866624);   //    32,768
  short* zt   = (short*)(ws + 3899392);   // 8,388,608  (total ~12.3MB)

  pack_b1s<<<2176, 256, 0, stream>>>(W1, Wg, B1h, B1l);
  pack_s  <<<1024, 256, 0, stream>>>(W2, W2h, W2l, 512, 512, 16, 32);
  pack_s  <<<64,   256, 0, stream>>>(W_init, WIh, WIl, 32, 512, 1, 32);
  pack_s  <<<1024, 256, 0, stream>>>(Wh1, Wh1p, (short*)nullptr, 512, 512, 16, 32);
  pack_s  <<<64,   256, 0, stream>>>(Wh2, Wh2p, (short*)nullptr, 512, 32, 16, 2);

  sde_kernel<<<16, 1024, 0, stream>>>(times, coeffs, dW, b_init, b1, b2, bg,
                                      B1h, B1l, W2h, W2l, WIh, WIl, zt);
  head_kernel<<<256, 256, 0, stream>>>(zt, Wh1p, Wh2p, bh1, bh2, out);
}

// Round 3
// 17538.690 us; speedup vs baseline: 1.2425x; 1.2425x over previous
//
#include <hip/hip_runtime.h>
#include <stdint.h>
#include <stddef.h>

typedef __attribute__((ext_vector_type(8))) short short8;
typedef __attribute__((ext_vector_type(8))) _Float16 half8;
typedef __attribute__((ext_vector_type(4))) float f32x4;

#define T_  256
#define B_  256
#define C_  32
#define H_  512
#define O_  32
#define KB1 17   // ceil(544/32)
#define NT1 64   // 64 col-tiles of 16 over [W1|Wg] (1024 ext cols)
#define KB2 16
#define NT2 32

__device__ __forceinline__ short f2h(float f) {
  _Float16 h = (_Float16)f;
  return __builtin_bit_cast(short, h);
}
__device__ __forceinline__ void f2hl(float f, short& hi, short& lo) {
  _Float16 h = (_Float16)f;
  _Float16 l = (_Float16)(f - (float)h);
  hi = __builtin_bit_cast(short, h);
  lo = __builtin_bit_cast(short, l);
}
__device__ __forceinline__ float fast_tanh(float x) {
  float e = __expf(2.0f * x);
  return 1.0f - 2.0f / (e + 1.0f);
}
__device__ __forceinline__ float fast_sigmoid(float x) {
  return 1.0f / (1.0f + __expf(-x));
}
__device__ __forceinline__ f32x4 mfma16(half8 a, half8 b, f32x4 c) {
  return __builtin_amdgcn_mfma_f32_16x16x32_f16(a, b, c, 0, 0, 0);
}
__device__ __forceinline__ half8 ld8(const short* p) { return *(const half8*)p; }

__device__ __forceinline__ void cvt8(const float4 v0, const float4 v1,
                                     short8& hi, short8& lo) {
  float a[8] = {v0.x, v0.y, v0.z, v0.w, v1.x, v1.y, v1.z, v1.w};
  #pragma unroll
  for (int j = 0; j < 8; ++j) { short h, l2; f2hl(a[j], h, l2); hi[j] = h; lo[j] = l2; }
}

// bg-local barrier: monotonic counter, 16 arrivals per phase.
__device__ __forceinline__ void bg_barrier(unsigned int* cnt, unsigned int target) {
  __threadfence();            // release: all prior global stores visible agent-wide
  __syncthreads();
  if (threadIdx.x == 0) {
    __hip_atomic_fetch_add(cnt, 1u, __ATOMIC_RELAXED, __HIP_MEMORY_SCOPE_AGENT);
    while (__hip_atomic_load(cnt, __ATOMIC_RELAXED, __HIP_MEMORY_SCOPE_AGENT) < target)
      __builtin_amdgcn_s_sleep(1);
  }
  __syncthreads();
  __threadfence();            // acquire: invalidate stale cached lines
}

// ---------------- weight packing (unchanged layout from passing round) ------
__global__ void pack_b1s(const float* __restrict__ W1, const float* __restrict__ Wg,
                         short* __restrict__ hi, short* __restrict__ lo) {
  int gid = blockIdx.x * 256 + threadIdx.x;          // 17*64*512
  if (gid >= KB1 * NT1 * 512) return;
  int j = gid & 7, lane = (gid >> 3) & 63, tile = gid >> 9;
  int nt = tile % NT1, kb = tile / NT1;
  int k = kb * 32 + ((lane >> 4) << 3) + j;
  int n = ((nt & 31) << 4) + (lane & 15);
  float v = 0.f;
  if (nt < 32)      v = W1[k * H_ + n];
  else if (k < H_)  v = Wg[k * H_ + n];
  short h, l;
  f2hl(v, h, l);
  hi[gid] = h; lo[gid] = l;
}

__global__ void pack_s(const float* __restrict__ src, short* __restrict__ hi,
                       short* __restrict__ lo, int Ksrc, int Nsrc, int KB, int NT) {
  int gid = blockIdx.x * 256 + threadIdx.x;
  if (gid >= KB * NT * 512) return;
  int j = gid & 7, lane = (gid >> 3) & 63, tile = gid >> 9;
  int nt = tile % NT, kb = tile / NT;
  int k = kb * 32 + ((lane >> 4) << 3) + j;
  int n = (nt << 4) + (lane & 15);
  float v = (k < Ksrc && n < Nsrc) ? src[k * Nsrc + n] : 0.f;
  short h, l;
  f2hl(v, h, l);
  hi[gid] = h;
  if (lo) lo[gid] = l;
}

// ---------------- SDE scan: 256 WGs (16 bg x 16 cg), weights in registers ----
__global__ __launch_bounds__(256, 1) void sde_kernel(
    const float* __restrict__ times, const float* __restrict__ coeffs,
    const float* __restrict__ dW,
    const float* __restrict__ b_init, const float* __restrict__ b1,
    const float* __restrict__ b2, const float* __restrict__ bgb,
    const short* __restrict__ B1h, const short* __restrict__ B1l,
    const short* __restrict__ W2h, const short* __restrict__ W2l,
    const short* __restrict__ WIh, const short* __restrict__ WIl,
    float* __restrict__ y_buf, float* __restrict__ h_buf,
    short* __restrict__ zt, unsigned int* __restrict__ cnt_base) {
  __shared__ short yx_hi[16][552];   // cols 0..511 y, 512..543 x_k
  __shared__ short yx_lo[16][552];
  __shared__ short hh_hi[16][520];
  __shared__ short hh_lo[16][520];
  __shared__ float g_x[16][32];
  __shared__ float redbuf[4];

  const int tid = threadIdx.x;
  const int w = tid >> 6, l = tid & 63;
  const int ra = l & 15, kq = l >> 4;
  const int bid = blockIdx.x;
  const int bg = bid & 15, cg = bid >> 4;
  const int R0 = bg << 4;
  unsigned int* cnt = cnt_base + bg * 32;     // 128B spacing

  // GEMM1 ntile for this wave: waves 0,1 -> h-tiles; 2,3 -> gate-tiles
  const int nt1w = (w < 2) ? (2 * cg + w) : (32 + 2 * cg + (w - 2));
  const int extcol = nt1w * 16 + ra;
  const int ntF = 2 * cg + (w & 1);           // GEMM2 tile (waves 0/1)
  const int fcol = ntF * 16 + ra;

  // ---- dt ----
  float d = 1e30f;
  if (tid < T_ - 1) d = times[tid + 1] - times[tid];
  #pragma unroll
  for (int s = 32; s >= 1; s >>= 1) d = fminf(d, __shfl_xor(d, s, 64));
  if (l == 0) redbuf[w] = d;

  // ---- load weight slices into registers (held for all 255 steps) ----
  half8 wb1h[17], wb1l[17];
  #pragma unroll
  for (int kb = 0; kb < 17; ++kb) {
    const size_t off = ((size_t)(kb * 64 + nt1w) << 9) + (l << 3);
    wb1h[kb] = ld8(B1h + off);
    wb1l[kb] = ld8(B1l + off);
  }
  half8 ww2h[16], ww2l[16];
  if (w < 2) {
    #pragma unroll
    for (int kb = 0; kb < 16; ++kb) {
      const size_t off = ((size_t)(kb * 32 + ntF) << 9) + (l << 3);
      ww2h[kb] = ld8(W2h + off);
      ww2l[kb] = ld8(W2l + off);
    }
  }

  // ---- stage x0 ----
  if (tid < 64) {
    int row = tid >> 2, cc = (tid & 3) << 3;
    const float* xb = coeffs + (size_t)(R0 + row) * (T_ * C_) + cc;
    float4 v0 = *(const float4*)xb;
    float4 v1 = *(const float4*)(xb + 4);
    short8 hi, lo;
    cvt8(v0, v1, hi, lo);
    *(short8*)&yx_hi[row][512 + cc] = hi;
    *(short8*)&yx_lo[row][512 + cc] = lo;
  }
  __syncthreads();
  float m = fminf(fminf(redbuf[0], redbuf[1]), fminf(redbuf[2], redbuf[3]));
  const float dt = fmaxf(m, 0.001f);
  const float sq = sqrtf(dt);

  const float b1v = (w < 2) ? b1[extcol] : 0.f;
  const float bgv = (w >= 2) ? bgb[extcol - 512] : 0.f;
  const float b2v = (w < 2) ? b2[fcol] : 0.f;

  // ---- z0 = x0 @ W_init + b_init (waves 0/1 own cols) ----
  float yr[4] = {0.f, 0.f, 0.f, 0.f};
  if (w < 2) {
    half8 ah = ld8(&yx_hi[ra][512 + (kq << 3)]);
    half8 al = ld8(&yx_lo[ra][512 + (kq << 3)]);
    half8 bh = ld8(WIh + ((size_t)ntF << 9) + (l << 3));
    half8 bl = ld8(WIl + ((size_t)ntF << 9) + (l << 3));
    f32x4 Z = {0.f, 0.f, 0.f, 0.f};
    Z = mfma16(ah, bh, Z); Z = mfma16(al, bh, Z); Z = mfma16(ah, bl, Z);
    float bi = b_init[fcol];
    #pragma unroll
    for (int r = 0; r < 4; ++r) {
      yr[r] = Z[r] + bi;
      y_buf[(size_t)(R0 + (kq << 2) + r) * H_ + fcol] = yr[r];
    }
  }
  bg_barrier(cnt, 16u);

  // ---- main scan ----
  for (int k = 0; k < T_ - 1; ++k) {
    float dwv[4];
    if (w < 2) {
      const float* dwb = dW + ((size_t)k * B_ + R0) * H_ + fcol;
      #pragma unroll
      for (int r = 0; r < 4; ++r)
        dwv[r] = dwb[((kq << 2) + r) * H_];
    }
    // stage y (from y_buf) + x_k
    {
      const float* yb = y_buf + (size_t)R0 * H_;
      #pragma unroll
      for (int i = 0; i < 4; ++i) {
        int chunk = i * 256 + tid;            // 1024 chunks of 8 floats
        int row = chunk >> 6, cc = (chunk & 63) << 3;
        float4 v0 = *(const float4*)(yb + row * H_ + cc);
        float4 v1 = *(const float4*)(yb + row * H_ + cc + 4);
        short8 hi, lo;
        cvt8(v0, v1, hi, lo);
        *(short8*)&yx_hi[row][cc] = hi;
        *(short8*)&yx_lo[row][cc] = lo;
      }
      if (tid < 64) {
        int row = tid >> 2, cc = (tid & 3) << 3;
        const float* xb = coeffs + (size_t)(R0 + row) * (T_ * C_) + (size_t)k * C_ + cc;
        float4 v0 = *(const float4*)xb;
        float4 v1 = *(const float4*)(xb + 4);
        short8 hi, lo;
        cvt8(v0, v1, hi, lo);
        *(short8*)&yx_hi[row][512 + cc] = hi;
        *(short8*)&yx_lo[row][512 + cc] = lo;
      }
    }
    __syncthreads();
    // GEMM1: 3-term split-fp16, B from registers
    f32x4 A = {0.f, 0.f, 0.f, 0.f};
    #pragma unroll
    for (int kb = 0; kb < 17; ++kb) {
      half8 ah = ld8(&yx_hi[ra][(kb << 5) + (kq << 3)]);
      half8 al = ld8(&yx_lo[ra][(kb << 5) + (kq << 3)]);
      A = mfma16(ah, wb1h[kb], A);
      A = mfma16(al, wb1h[kb], A);
      A = mfma16(ah, wb1l[kb], A);
    }
    if (w < 2) {
      #pragma unroll
      for (int r = 0; r < 4; ++r) {
        float h = fast_tanh(A[r] + b1v);
        h_buf[(size_t)(R0 + (kq << 2) + r) * H_ + extcol] = h;
      }
    } else {
      #pragma unroll
      for (int r = 0; r < 4; ++r)
        g_x[(kq << 2) + r][((w - 2) << 4) + ra] = fast_sigmoid(A[r] + bgv);
    }
    bg_barrier(cnt, 16u * (2u * (unsigned)k + 2u));
    // stage h
    {
      const float* hb = h_buf + (size_t)R0 * H_;
      #pragma unroll
      for (int i = 0; i < 4; ++i) {
        int chunk = i * 256 + tid;
        int row = chunk >> 6, cc = (chunk & 63) << 3;
        float4 v0 = *(const float4*)(hb + row * H_ + cc);
        float4 v1 = *(const float4*)(hb + row * H_ + cc + 4);
        short8 hi, lo;
        cvt8(v0, v1, hi, lo);
        *(short8*)&hh_hi[row][cc] = hi;
        *(short8*)&hh_lo[row][cc] = lo;
      }
    }
    __syncthreads();
    if (w < 2) {
      f32x4 F = {0.f, 0.f, 0.f, 0.f};
      #pragma unroll
      for (int kb = 0; kb < 16; ++kb) {
        half8 ah = ld8(&hh_hi[ra][(kb << 5) + (kq << 3)]);
        half8 al = ld8(&hh_lo[ra][(kb << 5) + (kq << 3)]);
        F = mfma16(ah, ww2h[kb], F);
        F = mfma16(al, ww2h[kb], F);
        F = mfma16(ah, ww2l[kb], F);
      }
      #pragma unroll
      for (int r = 0; r < 4; ++r) {
        float f = fast_tanh(F[r] + b2v);
        float g = g_x[(kq << 2) + r][((w & 1) << 4) + ra];
        yr[r] += f * dt + g * (sq * dwv[r]);
        y_buf[(size_t)(R0 + (kq << 2) + r) * H_ + fcol] = yr[r];
      }
      if (k >= T_ - 1 - O_) {
        int t = k - (T_ - 1 - O_);
        #pragma unroll
        for (int r = 0; r < 4; ++r)
          zt[((size_t)(R0 + (kq << 2) + r) * O_ + t) * H_ + fcol] = f2h(yr[r]);
      }
    }
    bg_barrier(cnt, 16u * (2u * (unsigned)k + 3u));
  }
}

// ---------------- head kernel (unchanged, fp16 single) ----------------
__global__ __launch_bounds__(256) void head_kernel(
    const short* __restrict__ zt, const short* __restrict__ Wh1p,
    const short* __restrict__ Wh2p, const float* __restrict__ bh1,
    const float* __restrict__ bh2, float* __restrict__ out) {
  __shared__ short a_lds[32][520];
  __shared__ short h2_lds[32][520];
  const int tid = threadIdx.x;
  const int w = tid >> 6, l = tid & 63;
  const int ra = l & 15, kq = l >> 4;
  const int r0 = blockIdx.x << 5;

  const short* zb = zt + (size_t)r0 * H_;
  #pragma unroll
  for (int i = 0; i < 8; ++i) {
    int cidx = i * 256 + tid;
    int row = cidx >> 6, cc = (cidx & 63) << 3;
    *(short8*)&a_lds[row][cc] = *(const short8*)(zb + row * H_ + cc);
  }
  __syncthreads();

  f32x4 acc[2][8];
  #pragma unroll
  for (int mt = 0; mt < 2; ++mt)
    #pragma unroll
    for (int i = 0; i < 8; ++i) acc[mt][i] = (f32x4){0.f, 0.f, 0.f, 0.f};
  for (int kb = 0; kb < 16; ++kb) {
    half8 a0 = ld8(&a_lds[ra][(kb << 5) + (kq << 3)]);
    half8 a1 = ld8(&a_lds[16 + ra][(kb << 5) + (kq << 3)]);
    const short* bp = Wh1p + (size_t)kb * (32 * 512) + (l << 3);
    #pragma unroll
    for (int i = 0; i < 8; ++i) {
      half8 b = ld8(bp + ((8 * w + i) << 9));
      acc[0][i] = mfma16(a0, b, acc[0][i]);
      acc[1][i] = mfma16(a1, b, acc[1][i]);
    }
  }
  #pragma unroll
  for (int i = 0; i < 8; ++i) {
    int col = ((8 * w + i) << 4) + ra;
    float bb = bh1[col];
    #pragma unroll
    for (int mt = 0; mt < 2; ++mt)
      #pragma unroll
      for (int r = 0; r < 4; ++r) {
        float h = acc[mt][i][r] + bb;
        h = h > 0.f ? h : 0.f;
        h2_lds[(mt << 4) + (kq << 2) + r][col] = f2h(h);
      }
  }
  __syncthreads();

  {
    int mt = w >> 1, nt = w & 1;
    f32x4 F = {0.f, 0.f, 0.f, 0.f};
    for (int kb = 0; kb < 16; ++kb) {
      half8 a = ld8(&h2_lds[(mt << 4) + ra][(kb << 5) + (kq << 3)]);
      half8 b = ld8(Wh2p + (size_t)((kb * 2 + nt) * 64 + l) * 8);
      F = mfma16(a, b, F);
    }
    int col = (nt << 4) + ra;
    float bb = bh2[col];
    #pragma unroll
    for (int r = 0; r < 4; ++r)
      out[(size_t)(r0 + (mt << 4) + (kq << 2) + r) * O_ + col] = F[r] + bb;
  }
}

// ---------------- launcher ----------------
extern "C" void kernel_launch(void* const* d_in, const int* in_sizes, int n_in,
                              void* d_out, int out_size, void* d_ws, size_t ws_size,
                              hipStream_t stream) {
  (void)in_sizes; (void)n_in; (void)out_size; (void)ws_size;
  const float* times  = (const float*)d_in[0];
  const float* coeffs = (const float*)d_in[1];
  const float* dW     = (const float*)d_in[3];
  const float* W_init = (const float*)d_in[4];
  const float* b_init = (const float*)d_in[5];
  const float* W1     = (const float*)d_in[6];
  const float* b1     = (const float*)d_in[7];
  const float* W2     = (const float*)d_in[8];
  const float* b2     = (const float*)d_in[9];
  const float* Wg     = (const float*)d_in[10];
  const float* bg     = (const float*)d_in[11];
  const float* Wh1    = (const float*)d_in[12];
  const float* bh1    = (const float*)d_in[13];
  const float* Wh2    = (const float*)d_in[14];
  const float* bh2    = (const float*)d_in[15];
  float* out = (float*)d_out;
  char* ws = (char*)d_ws;

  short* B1h  = (short*)(ws + 0);          // 1,114,112
  short* B1l  = (short*)(ws + 1114112);    // 1,114,112
  short* W2h  = (short*)(ws + 2228224);    //   524,288
  short* W2l  = (short*)(ws + 2752512);    //   524,288
  short* WIh  = (short*)(ws + 3276800);    //    32,768
  short* WIl  = (short*)(ws + 3309568);    //    32,768
  short* Wh1p = (short*)(ws + 3342336);    //   524,288
  short* Wh2p = (short*)(ws + 3866624);    //    32,768
  float* y_buf = (float*)(ws + 3899392);   //   524,288
  float* h_buf = (float*)(ws + 4423680);   //   524,288
  short* zt   = (short*)(ws + 4947968);    // 8,388,608
  unsigned int* cnt = (unsigned int*)(ws + 13336576);  // 16 * 128B

  pack_b1s<<<2176, 256, 0, stream>>>(W1, Wg, B1h, B1l);
  pack_s  <<<1024, 256, 0, stream>>>(W2, W2h, W2l, 512, 512, 16, 32);
  pack_s  <<<64,   256, 0, stream>>>(W_init, WIh, WIl, 32, 512, 1, 32);
  pack_s  <<<1024, 256, 0, stream>>>(Wh1, Wh1p, (short*)nullptr, 512, 512, 16, 32);
  pack_s  <<<64,   256, 0, stream>>>(Wh2, Wh2p, (short*)nullptr, 512, 32, 16, 2);

  hipMemsetAsync(ws + 13336576, 0, 2048, stream);

  sde_kernel<<<256, 256, 0, stream>>>(times, coeffs, dW, b_init, b1, b2, bg,
                                      B1h, B1l, W2h, W2l, WIh, WIl,
                                      y_buf, h_buf, zt, cnt);
  head_kernel<<<256, 256, 0, stream>>>(zt, Wh1p, Wh2p, bh1, bh2, out);
}

// Round 4
// 1501.688 us; speedup vs baseline: 14.5116x; 11.6793x over previous
//
#include <hip/hip_runtime.h>
#include <stdint.h>
#include <stddef.h>

typedef __attribute__((ext_vector_type(8))) short short8;
typedef __attribute__((ext_vector_type(2))) short short2v;
typedef __attribute__((ext_vector_type(8))) _Float16 half8;
typedef __attribute__((ext_vector_type(4))) float f32x4;
typedef unsigned long long ull;

#define T_  256
#define B_  256
#define C_  32
#define H_  512
#define O_  32
#define KB1 17
#define NT1 64
#define KB2 16
#define NT2 32

__device__ __forceinline__ short f2h(float f) {
  _Float16 h = (_Float16)f;
  return __builtin_bit_cast(short, h);
}
__device__ __forceinline__ void f2hl(float f, short& hi, short& lo) {
  _Float16 h = (_Float16)f;
  _Float16 l = (_Float16)(f - (float)h);
  hi = __builtin_bit_cast(short, h);
  lo = __builtin_bit_cast(short, l);
}
// pack value as {fp16 hi (low16), fp16 lo (high16)}
__device__ __forceinline__ unsigned int pack_hl(float f) {
  short h, l;
  f2hl(f, h, l);
  return (unsigned int)(unsigned short)h | ((unsigned int)(unsigned short)l << 16);
}
__device__ __forceinline__ float fast_tanh(float x) {
  float e = __expf(2.0f * x);
  return 1.0f - 2.0f / (e + 1.0f);
}
__device__ __forceinline__ float fast_sigmoid(float x) {
  return 1.0f / (1.0f + __expf(-x));
}
__device__ __forceinline__ f32x4 mfma16(half8 a, half8 b, f32x4 c) {
  return __builtin_amdgcn_mfma_f32_16x16x32_f16(a, b, c, 0, 0, 0);
}
__device__ __forceinline__ half8 ld8(const short* p) { return *(const half8*)p; }

// coherent (sc0 sc1) helpers — device-correct regardless of XCD placement
__device__ __forceinline__ void st_coh(unsigned int* p, unsigned int v) {
  __hip_atomic_store(p, v, __ATOMIC_RELAXED, __HIP_MEMORY_SCOPE_AGENT);
}
__device__ __forceinline__ ull ld_coh(const ull* p) {
  return __hip_atomic_load(p, __ATOMIC_RELAXED, __HIP_MEMORY_SCOPE_AGENT);
}

// stage 16 rows x 512 packed values from global into split hi/lo LDS tiles
__device__ __forceinline__ void stage_pk(const ull* src, short* hi, short* lo,
                                         int stride, int tid) {
  ull v[16];
  #pragma unroll
  for (int i = 0; i < 16; ++i) v[i] = ld_coh(src + i * 256 + tid);
  #pragma unroll
  for (int i = 0; i < 16; ++i) {
    int chunk = i * 256 + tid;
    int row = chunk >> 8, col = (chunk & 255) << 1;
    unsigned int u0 = (unsigned int)v[i], u1 = (unsigned int)(v[i] >> 32);
    short2v h2, l2;
    h2[0] = (short)(u0 & 0xffffu); h2[1] = (short)(u1 & 0xffffu);
    l2[0] = (short)(u0 >> 16);     l2[1] = (short)(u1 >> 16);
    *(short2v*)(hi + row * stride + col) = h2;
    *(short2v*)(lo + row * stride + col) = l2;
  }
}

// bg-local barrier: monotonic counter, NO threadfence (no L2 wb/inv).
// __syncthreads() emits s_waitcnt vmcnt(0) -> all sc0sc1 stores visible first.
__device__ __forceinline__ void bg_barrier(unsigned int* cnt, unsigned int target) {
  __syncthreads();
  if (threadIdx.x == 0) {
    __hip_atomic_fetch_add(cnt, 1u, __ATOMIC_RELAXED, __HIP_MEMORY_SCOPE_AGENT);
    while (__hip_atomic_load(cnt, __ATOMIC_RELAXED, __HIP_MEMORY_SCOPE_AGENT) < target)
      __builtin_amdgcn_s_sleep(1);
  }
  __syncthreads();
}

// ---------------- weight packing (layout unchanged) ----------------
__global__ void pack_b1s(const float* __restrict__ W1, const float* __restrict__ Wg,
                         short* __restrict__ hi, short* __restrict__ lo) {
  int gid = blockIdx.x * 256 + threadIdx.x;
  if (gid >= KB1 * NT1 * 512) return;
  int j = gid & 7, lane = (gid >> 3) & 63, tile = gid >> 9;
  int nt = tile % NT1, kb = tile / NT1;
  int k = kb * 32 + ((lane >> 4) << 3) + j;
  int n = ((nt & 31) << 4) + (lane & 15);
  float v = 0.f;
  if (nt < 32)      v = W1[k * H_ + n];
  else if (k < H_)  v = Wg[k * H_ + n];
  short h, l;
  f2hl(v, h, l);
  hi[gid] = h; lo[gid] = l;
}

__global__ void pack_s(const float* __restrict__ src, short* __restrict__ hi,
                       short* __restrict__ lo, int Ksrc, int Nsrc, int KB, int NT) {
  int gid = blockIdx.x * 256 + threadIdx.x;
  if (gid >= KB * NT * 512) return;
  int j = gid & 7, lane = (gid >> 3) & 63, tile = gid >> 9;
  int nt = tile % NT, kb = tile / NT;
  int k = kb * 32 + ((lane >> 4) << 3) + j;
  int n = (nt << 4) + (lane & 15);
  float v = (k < Ksrc && n < Nsrc) ? src[k * Nsrc + n] : 0.f;
  short h, l;
  f2hl(v, h, l);
  hi[gid] = h;
  if (lo) lo[gid] = l;
}

// ---------------- SDE scan: 256 WGs (16 bg x 16 cg), weights in registers ----
__global__ __launch_bounds__(256, 1) void sde_kernel(
    const float* __restrict__ times, const float* __restrict__ coeffs,
    const float* __restrict__ dW,
    const float* __restrict__ b_init, const float* __restrict__ b1,
    const float* __restrict__ b2, const float* __restrict__ bgb,
    const short* __restrict__ B1h, const short* __restrict__ B1l,
    const short* __restrict__ W2h, const short* __restrict__ W2l,
    const short* __restrict__ WIh, const short* __restrict__ WIl,
    unsigned int* __restrict__ y_pk, unsigned int* __restrict__ h_pk,
    short* __restrict__ zt, unsigned int* __restrict__ cnt_base) {
  __shared__ short yx_hi[16][552];
  __shared__ short yx_lo[16][552];
  __shared__ short hh_hi[16][520];
  __shared__ short hh_lo[16][520];
  __shared__ float g_x[16][32];
  __shared__ float redbuf[4];

  const int tid = threadIdx.x;
  const int w = tid >> 6, l = tid & 63;
  const int ra = l & 15, kq = l >> 4;
  const int bid = blockIdx.x;
  const int bg = bid & 15, cg = bid >> 4;
  const int R0 = bg << 4;
  unsigned int* cnt = cnt_base + bg * 32;

  const int nt1w = (w < 2) ? (2 * cg + w) : (32 + 2 * cg + (w - 2));
  const int extcol = nt1w * 16 + ra;
  const int ntF = 2 * cg + (w & 1);
  const int fcol = ntF * 16 + ra;

  float d = 1e30f;
  if (tid < T_ - 1) d = times[tid + 1] - times[tid];
  #pragma unroll
  for (int s = 32; s >= 1; s >>= 1) d = fminf(d, __shfl_xor(d, s, 64));
  if (l == 0) redbuf[w] = d;

  // weight slices -> registers (held for all 255 steps)
  half8 wb1h[17], wb1l[17];
  #pragma unroll
  for (int kb = 0; kb < 17; ++kb) {
    const size_t off = ((size_t)(kb * 64 + nt1w) << 9) + (l << 3);
    wb1h[kb] = ld8(B1h + off);
    wb1l[kb] = ld8(B1l + off);
  }
  half8 ww2h[16], ww2l[16];
  if (w < 2) {
    #pragma unroll
    for (int kb = 0; kb < 16; ++kb) {
      const size_t off = ((size_t)(kb * 32 + ntF) << 9) + (l << 3);
      ww2h[kb] = ld8(W2h + off);
      ww2l[kb] = ld8(W2l + off);
    }
  }

  // stage x0
  if (tid < 64) {
    int row = tid >> 2, cc = (tid & 3) << 3;
    const float* xb = coeffs + (size_t)(R0 + row) * (T_ * C_) + cc;
    #pragma unroll
    for (int j = 0; j < 8; ++j) {
      short h, lo;
      f2hl(xb[j], h, lo);
      yx_hi[row][512 + cc + j] = h;
      yx_lo[row][512 + cc + j] = lo;
    }
  }
  __syncthreads();
  float m = fminf(fminf(redbuf[0], redbuf[1]), fminf(redbuf[2], redbuf[3]));
  const float dt = fmaxf(m, 0.001f);
  const float sq = sqrtf(dt);

  const float b1v = (w < 2) ? b1[extcol] : 0.f;
  const float bgv = (w >= 2) ? bgb[extcol - 512] : 0.f;
  const float b2v = (w < 2) ? b2[fcol] : 0.f;

  // z0 = x0 @ W_init + b_init (waves 0/1 own cols)
  float yr[4] = {0.f, 0.f, 0.f, 0.f};
  if (w < 2) {
    half8 ah = ld8(&yx_hi[ra][512 + (kq << 3)]);
    half8 al = ld8(&yx_lo[ra][512 + (kq << 3)]);
    half8 bh = ld8(WIh + ((size_t)ntF << 9) + (l << 3));
    half8 bl = ld8(WIl + ((size_t)ntF << 9) + (l << 3));
    f32x4 Z = {0.f, 0.f, 0.f, 0.f};
    Z = mfma16(ah, bh, Z); Z = mfma16(al, bh, Z); Z = mfma16(ah, bl, Z);
    float bi = b_init[fcol];
    #pragma unroll
    for (int r = 0; r < 4; ++r) {
      yr[r] = Z[r] + bi;
      st_coh(&y_pk[(size_t)(R0 + (kq << 2) + r) * H_ + fcol], pack_hl(yr[r]));
    }
  }
  bg_barrier(cnt, 16u);

  // ---- main scan ----
  for (int k = 0; k < T_ - 1; ++k) {
    float dwv[4];
    if (w < 2) {
      const float* dwb = dW + ((size_t)k * B_ + R0) * H_ + fcol;
      #pragma unroll
      for (int r = 0; r < 4; ++r)
        dwv[r] = __builtin_nontemporal_load(dwb + ((kq << 2) + r) * H_);
    }
    // stage y (packed, coherent) + x_k (normal)
    stage_pk((const ull*)y_pk + R0 * 256, &yx_hi[0][0], &yx_lo[0][0], 552, tid);
    if (tid < 64) {
      int row = tid >> 2, cc = (tid & 3) << 3;
      const float* xb = coeffs + (size_t)(R0 + row) * (T_ * C_) + (size_t)k * C_ + cc;
      #pragma unroll
      for (int j = 0; j < 8; ++j) {
        short h, lo;
        f2hl(xb[j], h, lo);
        yx_hi[row][512 + cc + j] = h;
        yx_lo[row][512 + cc + j] = lo;
      }
    }
    __syncthreads();
    // GEMM1: 3-term split-fp16, B from registers
    f32x4 A = {0.f, 0.f, 0.f, 0.f};
    #pragma unroll
    for (int kb = 0; kb < 17; ++kb) {
      half8 ah = ld8(&yx_hi[ra][(kb << 5) + (kq << 3)]);
      half8 al = ld8(&yx_lo[ra][(kb << 5) + (kq << 3)]);
      A = mfma16(ah, wb1h[kb], A);
      A = mfma16(al, wb1h[kb], A);
      A = mfma16(ah, wb1l[kb], A);
    }
    if (w < 2) {
      #pragma unroll
      for (int r = 0; r < 4; ++r) {
        float h = fast_tanh(A[r] + b1v);
        st_coh(&h_pk[(size_t)(R0 + (kq << 2) + r) * H_ + extcol], pack_hl(h));
      }
    } else {
      #pragma unroll
      for (int r = 0; r < 4; ++r)
        g_x[(kq << 2) + r][((w - 2) << 4) + ra] = fast_sigmoid(A[r] + bgv);
    }
    bg_barrier(cnt, 16u * (2u * (unsigned)k + 2u));
    // stage h (packed, coherent)
    stage_pk((const ull*)h_pk + R0 * 256, &hh_hi[0][0], &hh_lo[0][0], 520, tid);
    __syncthreads();
    if (w < 2) {
      f32x4 F = {0.f, 0.f, 0.f, 0.f};
      #pragma unroll
      for (int kb = 0; kb < 16; ++kb) {
        half8 ah = ld8(&hh_hi[ra][(kb << 5) + (kq << 3)]);
        half8 al = ld8(&hh_lo[ra][(kb << 5) + (kq << 3)]);
        F = mfma16(ah, ww2h[kb], F);
        F = mfma16(al, ww2h[kb], F);
        F = mfma16(ah, ww2l[kb], F);
      }
      #pragma unroll
      for (int r = 0; r < 4; ++r) {
        float f = fast_tanh(F[r] + b2v);
        float g = g_x[(kq << 2) + r][((w & 1) << 4) + ra];
        yr[r] += f * dt + g * (sq * dwv[r]);
        st_coh(&y_pk[(size_t)(R0 + (kq << 2) + r) * H_ + fcol], pack_hl(yr[r]));
      }
      if (k >= T_ - 1 - O_) {
        int t = k - (T_ - 1 - O_);
        #pragma unroll
        for (int r = 0; r < 4; ++r)
          zt[((size_t)(R0 + (kq << 2) + r) * O_ + t) * H_ + fcol] = f2h(yr[r]);
      }
    }
    bg_barrier(cnt, 16u * (2u * (unsigned)k + 3u));
  }
}

// ---------------- head kernel (unchanged) ----------------
__global__ __launch_bounds__(256) void head_kernel(
    const short* __restrict__ zt, const short* __restrict__ Wh1p,
    const short* __restrict__ Wh2p, const float* __restrict__ bh1,
    const float* __restrict__ bh2, float* __restrict__ out) {
  __shared__ short a_lds[32][520];
  __shared__ short h2_lds[32][520];
  const int tid = threadIdx.x;
  const int w = tid >> 6, l = tid & 63;
  const int ra = l & 15, kq = l >> 4;
  const int r0 = blockIdx.x << 5;

  const short* zb = zt + (size_t)r0 * H_;
  #pragma unroll
  for (int i = 0; i < 8; ++i) {
    int cidx = i * 256 + tid;
    int row = cidx >> 6, cc = (cidx & 63) << 3;
    *(short8*)&a_lds[row][cc] = *(const short8*)(zb + row * H_ + cc);
  }
  __syncthreads();

  f32x4 acc[2][8];
  #pragma unroll
  for (int mt = 0; mt < 2; ++mt)
    #pragma unroll
    for (int i = 0; i < 8; ++i) acc[mt][i] = (f32x4){0.f, 0.f, 0.f, 0.f};
  for (int kb = 0; kb < 16; ++kb) {
    half8 a0 = ld8(&a_lds[ra][(kb << 5) + (kq << 3)]);
    half8 a1 = ld8(&a_lds[16 + ra][(kb << 5) + (kq << 3)]);
    const short* bp = Wh1p + (size_t)kb * (32 * 512) + (l << 3);
    #pragma unroll
    for (int i = 0; i < 8; ++i) {
      half8 b = ld8(bp + ((8 * w + i) << 9));
      acc[0][i] = mfma16(a0, b, acc[0][i]);
      acc[1][i] = mfma16(a1, b, acc[1][i]);
    }
  }
  #pragma unroll
  for (int i = 0; i < 8; ++i) {
    int col = ((8 * w + i) << 4) + ra;
    float bb = bh1[col];
    #pragma unroll
    for (int mt = 0; mt < 2; ++mt)
      #pragma unroll
      for (int r = 0; r < 4; ++r) {
        float h = acc[mt][i][r] + bb;
        h = h > 0.f ? h : 0.f;
        h2_lds[(mt << 4) + (kq << 2) + r][col] = f2h(h);
      }
  }
  __syncthreads();

  {
    int mt = w >> 1, nt = w & 1;
    f32x4 F = {0.f, 0.f, 0.f, 0.f};
    for (int kb = 0; kb < 16; ++kb) {
      half8 a = ld8(&h2_lds[(mt << 4) + ra][(kb << 5) + (kq << 3)]);
      half8 b = ld8(Wh2p + (size_t)((kb * 2 + nt) * 64 + l) * 8);
      F = mfma16(a, b, F);
    }
    int col = (nt << 4) + ra;
    float bb = bh2[col];
    #pragma unroll
    for (int r = 0; r < 4; ++r)
      out[(size_t)(r0 + (mt << 4) + (kq << 2) + r) * O_ + col] = F[r] + bb;
  }
}

// ---------------- launcher ----------------
extern "C" void kernel_launch(void* const* d_in, const int* in_sizes, int n_in,
                              void* d_out, int out_size, void* d_ws, size_t ws_size,
                              hipStream_t stream) {
  (void)in_sizes; (void)n_in; (void)out_size; (void)ws_size;
  const float* times  = (const float*)d_in[0];
  const float* coeffs = (const float*)d_in[1];
  const float* dW     = (const float*)d_in[3];
  const float* W_init = (const float*)d_in[4];
  const float* b_init = (const float*)d_in[5];
  const float* W1     = (const float*)d_in[6];
  const float* b1     = (const float*)d_in[7];
  const float* W2     = (const float*)d_in[8];
  const float* b2     = (const float*)d_in[9];
  const float* Wg     = (const float*)d_in[10];
  const float* bg     = (const float*)d_in[11];
  const float* Wh1    = (const float*)d_in[12];
  const float* bh1    = (const float*)d_in[13];
  const float* Wh2    = (const float*)d_in[14];
  const float* bh2    = (const float*)d_in[15];
  float* out = (float*)d_out;
  char* ws = (char*)d_ws;

  short* B1h  = (short*)(ws + 0);          // 1,114,112
  short* B1l  = (short*)(ws + 1114112);    // 1,114,112
  short* W2h  = (short*)(ws + 2228224);    //   524,288
  short* W2l  = (short*)(ws + 2752512);    //   524,288
  short* WIh  = (short*)(ws + 3276800);    //    32,768
  short* WIl  = (short*)(ws + 3309568);    //    32,768
  short* Wh1p = (short*)(ws + 3342336);    //   524,288
  short* Wh2p = (short*)(ws + 3866624);    //    32,768
  unsigned int* y_pk = (unsigned int*)(ws + 3899392);  // 524,288
  unsigned int* h_pk = (unsigned int*)(ws + 4423680);  // 524,288
  short* zt   = (short*)(ws + 4947968);    // 8,388,608
  unsigned int* cnt = (unsigned int*)(ws + 13336576);  // 2048

  pack_b1s<<<2176, 256, 0, stream>>>(W1, Wg, B1h, B1l);
  pack_s  <<<1024, 256, 0, stream>>>(W2, W2h, W2l, 512, 512, 16, 32);
  pack_s  <<<64,   256, 0, stream>>>(W_init, WIh, WIl, 32, 512, 1, 32);
  pack_s  <<<1024, 256, 0, stream>>>(Wh1, Wh1p, (short*)nullptr, 512, 512, 16, 32);
  pack_s  <<<64,   256, 0, stream>>>(Wh2, Wh2p, (short*)nullptr, 512, 32, 16, 2);

  hipMemsetAsync(ws + 13336576, 0, 2048, stream);

  sde_kernel<<<256, 256, 0, stream>>>(times, coeffs, dW, b_init, b1, b2, bg,
                                      B1h, B1l, W2h, W2l, WIh, WIl,
                                      y_pk, h_pk, zt, cnt);
  head_kernel<<<256, 256, 0, stream>>>(zt, Wh1p, Wh2p, bh1, bh2, out);
}